// Round 1
// baseline (5686.782 us; speedup 1.0000x reference)
//
#include <hip/hip_runtime.h>

#define DD  128   // feature dim
#define TR  64    // rows (edges/nodes) per workgroup tile
#define LDH 65    // transposed LDS h stride (k-major), conflict-free

// ---------------------------------------------------------------------------
// Edge MLP: h = relu([v_i, v_j, ef] @ ew1 + eb1); h = relu(h@ew2+eb2);
//           h = h@ew3+eb3; new_e = LN(h)*g+beta;
//           out_e = new_e + ef;  atomicAdd(agg[recv], new_e)
// Layout: 256 thr = 4 waves; lane = row (edge in tile); wave = 32-col chunk.
// Weights are wave-uniform (c0 via readfirstlane) -> scalar/broadcast loads.
// Inter-layer h goes through transposed LDS ht[k][row] (stride 65: the
// (k*65+row)%32 bank index varies with row -> 2-way max = free).
// ---------------------------------------------------------------------------
__global__ __launch_bounds__(256, 4) void edge_mlp_kernel(
    const float* __restrict__ node, const float* __restrict__ efeat,
    const int* __restrict__ snd, const int* __restrict__ rcv,
    const float* __restrict__ w1, const float* __restrict__ b1,
    const float* __restrict__ w2, const float* __restrict__ b2,
    const float* __restrict__ w3, const float* __restrict__ b3,
    const float* __restrict__ gg, const float* __restrict__ bb,
    float* __restrict__ out_e, float* __restrict__ agg, int E)
{
    __shared__ float ht[DD * LDH];
    __shared__ float red1[4 * TR];
    __shared__ float red2[4 * TR];

    const int tid = (int)threadIdx.x;
    const int row = tid & 63;
    const int c0  = __builtin_amdgcn_readfirstlane((tid >> 6) << 5);
    const long e0 = (long)blockIdx.x * TR;
    const int  e  = (int)e0 + row;
    const bool valid = (e < E);
    const int  eS = valid ? e : 0;

    const int sj = snd[eS];
    const int rj = rcv[eS];

    const float* vi = node  + (long)sj * DD;
    const float* vj = node  + (long)rj * DD;
    const float* ve = efeat + (long)eS * DD;

    float acc[32];

    // ---- layer 1: [v_i | v_j | ef] @ ew1 + eb1, relu ----
#pragma unroll
    for (int i = 0; i < 32; ++i) acc[i] = b1[c0 + i];
    {
        const float* W = w1 + c0;                 // rows 0..127 (v_i block)
#pragma unroll 4
        for (int k = 0; k < DD; ++k) {
            const float xk = vi[k];
            const float* wr = W + k * DD;
#pragma unroll
            for (int i = 0; i < 32; ++i) acc[i] = fmaf(wr[i], xk, acc[i]);
        }
    }
    {
        const float* W = w1 + 128 * DD + c0;      // rows 128..255 (v_j block)
#pragma unroll 4
        for (int k = 0; k < DD; ++k) {
            const float xk = vj[k];
            const float* wr = W + k * DD;
#pragma unroll
            for (int i = 0; i < 32; ++i) acc[i] = fmaf(wr[i], xk, acc[i]);
        }
    }
    {
        const float* W = w1 + 256 * DD + c0;      // rows 256..383 (ef block)
#pragma unroll 4
        for (int k = 0; k < DD; ++k) {
            const float xk = ve[k];
            const float* wr = W + k * DD;
#pragma unroll
            for (int i = 0; i < 32; ++i) acc[i] = fmaf(wr[i], xk, acc[i]);
        }
    }
#pragma unroll
    for (int i = 0; i < 32; ++i) ht[(c0 + i) * LDH + row] = fmaxf(acc[i], 0.f);
    __syncthreads();

    // ---- layer 2: h @ ew2 + eb2, relu ----
#pragma unroll
    for (int i = 0; i < 32; ++i) acc[i] = b2[c0 + i];
    {
        const float* W = w2 + c0;
#pragma unroll 4
        for (int k = 0; k < DD; ++k) {
            const float xk = ht[k * LDH + row];
            const float* wr = W + k * DD;
#pragma unroll
            for (int i = 0; i < 32; ++i) acc[i] = fmaf(wr[i], xk, acc[i]);
        }
    }
    __syncthreads();   // all reads of ht done before in-place overwrite
#pragma unroll
    for (int i = 0; i < 32; ++i) ht[(c0 + i) * LDH + row] = fmaxf(acc[i], 0.f);
    __syncthreads();

    // ---- layer 3: h @ ew3 + eb3 (no relu) ----
#pragma unroll
    for (int i = 0; i < 32; ++i) acc[i] = b3[c0 + i];
    {
        const float* W = w3 + c0;
#pragma unroll 4
        for (int k = 0; k < DD; ++k) {
            const float xk = ht[k * LDH + row];
            const float* wr = W + k * DD;
#pragma unroll
            for (int i = 0; i < 32; ++i) acc[i] = fmaf(wr[i], xk, acc[i]);
        }
    }

    // ---- LayerNorm across 128 cols of each row (4 wave-partials via LDS) ----
    float s1 = 0.f, s2 = 0.f;
#pragma unroll
    for (int i = 0; i < 32; ++i) { s1 += acc[i]; s2 += acc[i] * acc[i]; }
    red1[(tid >> 6) * TR + row] = s1;
    red2[(tid >> 6) * TR + row] = s2;
    __syncthreads();
    const float S1 = red1[row] + red1[TR + row] + red1[2 * TR + row] + red1[3 * TR + row];
    const float S2 = red2[row] + red2[TR + row] + red2[2 * TR + row] + red2[3 * TR + row];
    const float mu   = S1 * (1.0f / 128.0f);
    const float var  = S2 * (1.0f / 128.0f) - mu * mu;
    const float rstd = rsqrtf(var + 1e-5f);

    if (valid) {
        float*       op = out_e + (long)e * DD + c0;
        float*       ap = agg   + (long)rj * DD + c0;
        const float* er = efeat + (long)e * DD + c0;
#pragma unroll
        for (int i = 0; i < 32; i += 4) {
            const float t0 = (acc[i + 0] - mu) * rstd * gg[c0 + i + 0] + bb[c0 + i + 0];
            const float t1 = (acc[i + 1] - mu) * rstd * gg[c0 + i + 1] + bb[c0 + i + 1];
            const float t2 = (acc[i + 2] - mu) * rstd * gg[c0 + i + 2] + bb[c0 + i + 2];
            const float t3 = (acc[i + 3] - mu) * rstd * gg[c0 + i + 3] + bb[c0 + i + 3];
            float4 o;
            o.x = t0 + er[i + 0];
            o.y = t1 + er[i + 1];
            o.z = t2 + er[i + 2];
            o.w = t3 + er[i + 3];
            *(float4*)(op + i) = o;
            atomicAdd(ap + i + 0, t0);   // segment-sum of new_e (pre-residual)
            atomicAdd(ap + i + 1, t1);
            atomicAdd(ap + i + 2, t2);
            atomicAdd(ap + i + 3, t3);
        }
    }
}

// ---------------------------------------------------------------------------
// Node MLP: x = [node, agg, 0]; h = relu(x@nw1+nb1) (zero block skipped);
//           h = relu(h@nw2+nb2); h = h@nw3+nb3; out = LN(h)*g+beta + node
// ---------------------------------------------------------------------------
__global__ __launch_bounds__(256, 4) void node_mlp_kernel(
    const float* __restrict__ node, const float* __restrict__ agg,
    const float* __restrict__ w1, const float* __restrict__ b1,
    const float* __restrict__ w2, const float* __restrict__ b2,
    const float* __restrict__ w3, const float* __restrict__ b3,
    const float* __restrict__ gg, const float* __restrict__ bb,
    float* __restrict__ out_n, int N)
{
    __shared__ float ht[DD * LDH];
    __shared__ float red1[4 * TR];
    __shared__ float red2[4 * TR];

    const int tid = (int)threadIdx.x;
    const int row = tid & 63;
    const int c0  = __builtin_amdgcn_readfirstlane((tid >> 6) << 5);
    const long n0 = (long)blockIdx.x * TR;
    const int  n  = (int)n0 + row;
    const bool valid = (n < N);
    const int  nS = valid ? n : 0;

    const float* vn = node + (long)nS * DD;
    const float* va = agg  + (long)nS * DD;

    float acc[32];

    // ---- layer 1: node @ nw1[0:128] + agg @ nw1[128:256] + nb1, relu ----
#pragma unroll
    for (int i = 0; i < 32; ++i) acc[i] = b1[c0 + i];
    {
        const float* W = w1 + c0;
#pragma unroll 4
        for (int k = 0; k < DD; ++k) {
            const float xk = vn[k];
            const float* wr = W + k * DD;
#pragma unroll
            for (int i = 0; i < 32; ++i) acc[i] = fmaf(wr[i], xk, acc[i]);
        }
    }
    {
        const float* W = w1 + 128 * DD + c0;
#pragma unroll 4
        for (int k = 0; k < DD; ++k) {
            const float xk = va[k];
            const float* wr = W + k * DD;
#pragma unroll
            for (int i = 0; i < 32; ++i) acc[i] = fmaf(wr[i], xk, acc[i]);
        }
    }
    // third input block is all zeros -> skipped entirely
#pragma unroll
    for (int i = 0; i < 32; ++i) ht[(c0 + i) * LDH + row] = fmaxf(acc[i], 0.f);
    __syncthreads();

    // ---- layer 2 ----
#pragma unroll
    for (int i = 0; i < 32; ++i) acc[i] = b2[c0 + i];
    {
        const float* W = w2 + c0;
#pragma unroll 4
        for (int k = 0; k < DD; ++k) {
            const float xk = ht[k * LDH + row];
            const float* wr = W + k * DD;
#pragma unroll
            for (int i = 0; i < 32; ++i) acc[i] = fmaf(wr[i], xk, acc[i]);
        }
    }
    __syncthreads();
#pragma unroll
    for (int i = 0; i < 32; ++i) ht[(c0 + i) * LDH + row] = fmaxf(acc[i], 0.f);
    __syncthreads();

    // ---- layer 3 ----
#pragma unroll
    for (int i = 0; i < 32; ++i) acc[i] = b3[c0 + i];
    {
        const float* W = w3 + c0;
#pragma unroll 4
        for (int k = 0; k < DD; ++k) {
            const float xk = ht[k * LDH + row];
            const float* wr = W + k * DD;
#pragma unroll
            for (int i = 0; i < 32; ++i) acc[i] = fmaf(wr[i], xk, acc[i]);
        }
    }

    // ---- LayerNorm ----
    float s1 = 0.f, s2 = 0.f;
#pragma unroll
    for (int i = 0; i < 32; ++i) { s1 += acc[i]; s2 += acc[i] * acc[i]; }
    red1[(tid >> 6) * TR + row] = s1;
    red2[(tid >> 6) * TR + row] = s2;
    __syncthreads();
    const float S1 = red1[row] + red1[TR + row] + red1[2 * TR + row] + red1[3 * TR + row];
    const float S2 = red2[row] + red2[TR + row] + red2[2 * TR + row] + red2[3 * TR + row];
    const float mu   = S1 * (1.0f / 128.0f);
    const float var  = S2 * (1.0f / 128.0f) - mu * mu;
    const float rstd = rsqrtf(var + 1e-5f);

    if (valid) {
        float*       op = out_n + (long)n * DD + c0;
        const float* nr = node  + (long)n * DD + c0;
#pragma unroll
        for (int i = 0; i < 32; i += 4) {
            float4 o;
            o.x = (acc[i + 0] - mu) * rstd * gg[c0 + i + 0] + bb[c0 + i + 0] + nr[i + 0];
            o.y = (acc[i + 1] - mu) * rstd * gg[c0 + i + 1] + bb[c0 + i + 1] + nr[i + 1];
            o.z = (acc[i + 2] - mu) * rstd * gg[c0 + i + 2] + bb[c0 + i + 2] + nr[i + 2];
            o.w = (acc[i + 3] - mu) * rstd * gg[c0 + i + 3] + bb[c0 + i + 3] + nr[i + 3];
            *(float4*)(op + i) = o;
        }
    }
}

extern "C" void kernel_launch(void* const* d_in, const int* in_sizes, int n_in,
                              void* d_out, int out_size, void* d_ws, size_t ws_size,
                              hipStream_t stream)
{
    const float* node  = (const float*)d_in[0];
    const float* efeat = (const float*)d_in[1];
    const int*   snd   = (const int*)d_in[2];
    const int*   rcv   = (const int*)d_in[3];
    const float* ew1 = (const float*)d_in[4],  *eb1 = (const float*)d_in[5];
    const float* ew2 = (const float*)d_in[6],  *eb2 = (const float*)d_in[7];
    const float* ew3 = (const float*)d_in[8],  *eb3 = (const float*)d_in[9];
    const float* eg  = (const float*)d_in[10], *ebeta = (const float*)d_in[11];
    const float* nw1 = (const float*)d_in[12], *nb1 = (const float*)d_in[13];
    const float* nw2 = (const float*)d_in[14], *nb2 = (const float*)d_in[15];
    const float* nw3 = (const float*)d_in[16], *nb3 = (const float*)d_in[17];
    const float* ng  = (const float*)d_in[18], *nbeta = (const float*)d_in[19];

    const int N = in_sizes[0] / DD;   // 100000
    const int E = in_sizes[2];        // 600000

    float* agg   = (float*)d_ws;                  // N*DD floats of scratch
    float* out_n = (float*)d_out;                 // new_n + node  (N*DD)
    float* out_e = (float*)d_out + (long)N * DD;  // new_e + ef    (E*DD)

    // ws is re-poisoned to 0xAA before every launch -> zero the accumulator
    hipMemsetAsync(agg, 0, (size_t)N * DD * sizeof(float), stream);

    const int eBlocks = (E + TR - 1) / TR;
    hipLaunchKernelGGL(edge_mlp_kernel, dim3(eBlocks), dim3(256), 0, stream,
                       node, efeat, snd, rcv, ew1, eb1, ew2, eb2, ew3, eb3,
                       eg, ebeta, out_e, agg, E);

    const int nBlocks = (N + TR - 1) / TR;
    hipLaunchKernelGGL(node_mlp_kernel, dim3(nBlocks), dim3(256), 0, stream,
                       node, agg, nw1, nb1, nw2, nb2, nw3, nb3,
                       ng, nbeta, out_n, N);
}